// Round 1
// baseline (126.545 us; speedup 1.0000x reference)
//
#include <hip/hip_runtime.h>
#include <stdint.h>

#define SEQ 4096
#define FDIM 128
#define NH 4
#define HD 32
#define NB 2
#define LRELU_ALPHA 0.2f

typedef float f32x4 __attribute__((ext_vector_type(4)));
typedef __bf16 bf16x8 __attribute__((ext_vector_type(8)));
typedef unsigned int u32x4 __attribute__((ext_vector_type(4)));

__device__ __forceinline__ unsigned short f2bf(float f) {
  unsigned int u = __builtin_bit_cast(unsigned int, f);
  return (unsigned short)((u + 0x7FFFu + ((u >> 16) & 1u)) >> 16);  // RTNE
}

// ---- pre-pass 1: fp32 -> bf16 ----
__global__ void cvt_kernel(const float* __restrict__ in, unsigned short* __restrict__ out) {
  int i = (blockIdx.x * 256 + threadIdx.x) * 4;
  float4 v = *reinterpret_cast<const float4*>(in + i);
  ushort4 o;
  o.x = f2bf(v.x); o.y = f2bf(v.y); o.z = f2bf(v.z); o.w = f2bf(v.w);
  *reinterpret_cast<ushort4*>(out + i) = o;
}

// ---- pre-pass 2: adjacency int32 -> bitmask (bit j of word = adj[i][j]!=0) ----
__global__ void adjpack_kernel(const int* __restrict__ adj, unsigned long long* __restrict__ bits) {
  size_t t = (size_t)blockIdx.x * 256 + threadIdx.x;
  int v = adj[t];
  unsigned long long m = __ballot(v != 0);
  if ((threadIdx.x & 63) == 0) bits[t >> 6] = m;
}

// ---- main fused attention kernel ----
// Grid: (SEQ/64, NB*NH). 4 waves/block, each wave owns 16 q-rows.
__global__ __launch_bounds__(256) void gat_kernel(
    const unsigned short* __restrict__ xbf,
    const unsigned long long* __restrict__ bits,
    float* __restrict__ out) {
  __shared__ __align__(16) unsigned short Kl[64][40];  // K tile, padded (80B rows)
  __shared__ __align__(16) unsigned short Vt[32][68];  // V^T tile, padded (136B rows)

  const int bh = blockIdx.y;
  const int b = bh >> 2;
  const int h = bh & 3;
  const int tid = threadIdx.x;
  const int wid = tid >> 6;
  const int lane = tid & 63;
  const int g = lane >> 4;    // lane group 0..3
  const int ql = lane & 15;   // this lane's q-row within wave tile (score/P rows)
  const int qw = blockIdx.x * 64 + wid * 16;

  const unsigned short* xb = xbf + ((size_t)b * SEQ) * FDIM + h * HD;

  // Q fragment: row ql, k = g*8..g*8+7 (same per-lane k-chunk convention as K frags)
  bf16x8 qf = __builtin_bit_cast(bf16x8,
      *reinterpret_cast<const uint4*>(xb + (size_t)(qw + ql) * FDIM + g * 8));

  f32x4 acc0 = {0.f, 0.f, 0.f, 0.f};  // O cols 0..15   (row = 4g+r, col = ql)
  f32x4 acc1 = {0.f, 0.f, 0.f, 0.f};  // O cols 16..31
  float mrun = -INFINITY;
  float lrun = 0.f;

  const unsigned long long* brow = bits + (size_t)(qw + ql) * (SEQ / 64);

  const int srow = tid >> 2;  // staging: row 0..63
  const int sq4 = tid & 3;    // staging: 8-col chunk

  for (int j0 = 0; j0 < SEQ; j0 += 64) {
    __syncthreads();
    // stage K tile (row-major, padded) + V^T tile
    uint4 d = *reinterpret_cast<const uint4*>(xb + (size_t)(j0 + srow) * FDIM + sq4 * 8);
    *reinterpret_cast<uint4*>(&Kl[srow][sq4 * 8]) = d;
    union { uint4 u; unsigned short s[8]; } du;
    du.u = d;
#pragma unroll
    for (int e = 0; e < 8; ++e) Vt[sq4 * 8 + e][srow] = du.s[e];
    __syncthreads();

    // swapped QK^T: D[a=j-local][b=q]; lane holds S[q=ql][j = 16t + 4g + r]
    f32x4 sc[4];
#pragma unroll
    for (int t = 0; t < 4; ++t) {
      bf16x8 kf = __builtin_bit_cast(bf16x8,
          *reinterpret_cast<const uint4*>(&Kl[t * 16 + ql][g * 8]));
      f32x4 z = {0.f, 0.f, 0.f, 0.f};
      sc[t] = __builtin_amdgcn_mfma_f32_16x16x32_bf16(kf, qf, z, 0, 0, 0);
    }

    const unsigned long long w64 = brow[j0 >> 6];
    float p[4][4];
    float tmax = -INFINITY;
#pragma unroll
    for (int t = 0; t < 4; ++t) {
#pragma unroll
      for (int r = 0; r < 4; ++r) {
        float v = sc[t][r];
        v = v > 0.f ? v : LRELU_ALPHA * v;          // leaky_relu
        const int jb = t * 16 + g * 4 + r;          // j within this 64-tile
        v = ((w64 >> jb) & 1ull) ? v : -INFINITY;   // adjacency mask
        p[t][r] = v;
        tmax = fmaxf(tmax, v);
      }
    }
    // row reduce across the 4 replicated lane-groups
    tmax = fmaxf(tmax, __shfl_xor(tmax, 16));
    tmax = fmaxf(tmax, __shfl_xor(tmax, 32));

    const float mnew = fmaxf(mrun, tmax);
    const float scale = __expf(mrun - mnew);  // first tile: exp(-inf)=0
    float rsum = 0.f;
#pragma unroll
    for (int t = 0; t < 4; ++t)
#pragma unroll
      for (int r = 0; r < 4; ++r) {
        const float e = __expf(p[t][r] - mnew);
        p[t][r] = e;
        rsum += e;
      }
    rsum += __shfl_xor(rsum, 16);
    rsum += __shfl_xor(rsum, 32);
    lrun = lrun * scale + rsum;
    mrun = mnew;

    // rescale O: accumulator rows are 4g+r -> fetch that row's scale via shfl
#pragma unroll
    for (int r = 0; r < 4; ++r) {
      const float s4 = __shfl(scale, g * 4 + r);
      acc0[r] *= s4;
      acc1[r] *= s4;
    }

    // PV: P (16 x 64) x V (64 x 32), two K=32 chunks (u), two col chunks (cc).
    // A-frag slot (g, tp*4+r) <-> j = 32u + 16tp + 4g + r ; V loaded in the same order.
#pragma unroll
    for (int u = 0; u < 2; ++u) {
      bf16x8 pa;
#pragma unroll
      for (int tp = 0; tp < 2; ++tp)
#pragma unroll
        for (int r = 0; r < 4; ++r)
          pa[tp * 4 + r] = __builtin_bit_cast(__bf16, f2bf(p[2 * u + tp][r]));
#pragma unroll
      for (int cc = 0; cc < 2; ++cc) {
        const unsigned short* vp = &Vt[cc * 16 + ql][u * 32 + g * 4];
        uint2 v0 = *reinterpret_cast<const uint2*>(vp);       // j = 32u +  0 + 4g + r
        uint2 v1 = *reinterpret_cast<const uint2*>(vp + 16);  // j = 32u + 16 + 4g + r
        u32x4 vv = {v0.x, v0.y, v1.x, v1.y};
        bf16x8 vf = __builtin_bit_cast(bf16x8, vv);
        if (cc == 0)
          acc0 = __builtin_amdgcn_mfma_f32_16x16x32_bf16(pa, vf, acc0, 0, 0, 0);
        else
          acc1 = __builtin_amdgcn_mfma_f32_16x16x32_bf16(pa, vf, acc1, 0, 0, 0);
      }
    }
  }

  // epilogue: O[row=4g+r][col=ql (+16)] / l_row
#pragma unroll
  for (int r = 0; r < 4; ++r) {
    const float lr = __shfl(lrun, g * 4 + r);
    const float inv = 1.f / lr;
    const size_t o = ((size_t)b * SEQ + (size_t)(qw + g * 4 + r)) * FDIM + h * HD;
    out[o + ql] = acc0[r] * inv;
    out[o + 16 + ql] = acc1[r] * inv;
  }
}

extern "C" void kernel_launch(void* const* d_in, const int* in_sizes, int n_in,
                              void* d_out, int out_size, void* d_ws, size_t ws_size,
                              hipStream_t stream) {
  (void)in_sizes; (void)n_in; (void)out_size; (void)ws_size;
  const float* x = (const float*)d_in[0];
  const int* adj = (const int*)d_in[1];
  float* outp = (float*)d_out;

  unsigned short* xbf = (unsigned short*)d_ws;                                  // 2 MiB
  unsigned long long* bits = (unsigned long long*)((char*)d_ws + (2u << 20));   // 2 MiB

  cvt_kernel<<<(NB * SEQ * FDIM) / (256 * 4), 256, 0, stream>>>(x, xbf);
  adjpack_kernel<<<(SEQ * SEQ) / (256 * 64) * 64, 256, 0, stream>>>(adj, bits);
  dim3 grid(SEQ / 64, NB * NH);
  gat_kernel<<<grid, 256, 0, stream>>>(xbf, bits, outp);
}

// Round 2
// 82.955 us; speedup vs baseline: 1.5255x; 1.5255x over previous
//
#include <hip/hip_runtime.h>
#include <stdint.h>

#define SEQ 4096
#define FDIM 128
#define NH 4
#define HD 32
#define NB 2
#define NROWS (NB * NH * SEQ)  // 32768
#define LOG2E 1.4426950408889634f
#define NEGBIG (-1.0e30f)
#define DEFER_THR 11.5f  // ~8 nats in log2 domain

typedef float f32x4 __attribute__((ext_vector_type(4)));
typedef __bf16 bf16x8 __attribute__((ext_vector_type(8)));

__device__ __forceinline__ unsigned short f2bf(float f) {
  unsigned int u = __builtin_bit_cast(unsigned int, f);
  return (unsigned short)((u + 0x7FFFu + ((u >> 16) & 1u)) >> 16);  // RTNE
}

// ---- pre-pass 1: fp32 -> bf16 ----
__global__ void cvt_kernel(const float* __restrict__ in, unsigned short* __restrict__ out) {
  int i = (blockIdx.x * 256 + threadIdx.x) * 4;
  float4 v = *reinterpret_cast<const float4*>(in + i);
  ushort4 o;
  o.x = f2bf(v.x); o.y = f2bf(v.y); o.z = f2bf(v.z); o.w = f2bf(v.w);
  *reinterpret_cast<ushort4*>(out + i) = o;
}

// ---- pre-pass 2: adjacency int32 -> bitmask; 16 ints/thread ----
__global__ void adjpack_kernel(const int* __restrict__ adj, unsigned short* __restrict__ bits16) {
  size_t t = (size_t)blockIdx.x * 256 + threadIdx.x;
  const uint4* p = reinterpret_cast<const uint4*>(adj) + t * 4;
  uint4 a = p[0], b = p[1], c = p[2], d = p[3];
  unsigned m = 0;
  m |= (a.x != 0) ? 1u : 0u;        m |= (a.y != 0) ? 2u : 0u;
  m |= (a.z != 0) ? 4u : 0u;        m |= (a.w != 0) ? 8u : 0u;
  m |= (b.x != 0) ? 16u : 0u;       m |= (b.y != 0) ? 32u : 0u;
  m |= (b.z != 0) ? 64u : 0u;       m |= (b.w != 0) ? 128u : 0u;
  m |= (c.x != 0) ? 256u : 0u;      m |= (c.y != 0) ? 512u : 0u;
  m |= (c.z != 0) ? 1024u : 0u;     m |= (c.w != 0) ? 2048u : 0u;
  m |= (d.x != 0) ? 4096u : 0u;     m |= (d.y != 0) ? 8192u : 0u;
  m |= (d.z != 0) ? 16384u : 0u;    m |= (d.w != 0) ? 32768u : 0u;
  bits16[t] = (unsigned short)m;
}

// ---- main fused attention kernel ----
// Grid: (SEQ/64, NB*NH, NSPLIT). 4 waves/block, each wave owns 16 q-rows.
template <int NSPLIT>
__global__ __launch_bounds__(256) void gat_kernel(
    const unsigned short* __restrict__ xbf,
    const unsigned long long* __restrict__ bits,
    float* __restrict__ dst,   // NSPLIT==1: final out ; else: Opart
    float* __restrict__ ml) {  // NSPLIT>1 only: [split][row][2] = (m, l)
  __shared__ __align__(16) unsigned short Kl[64][40];  // row-major K tile (80B rows)
  __shared__ __align__(16) unsigned short Vt[32][68];  // V^T tile (136B rows)

  const int bh = blockIdx.y;
  const int b = bh >> 2;
  const int h = bh & 3;
  const int tid = threadIdx.x;
  const int wid = tid >> 6;
  const int lane = tid & 63;
  const int g = lane >> 4;
  const int ql = lane & 15;
  const int qw = blockIdx.x * 64 + wid * 16;
  const int jbase = blockIdx.z * (SEQ / NSPLIT);
  const int NT = (SEQ / NSPLIT) / 64;

  const unsigned short* xb = xbf + ((size_t)b * SEQ) * FDIM + h * HD;

  // Q fragment, pre-scaled by log2(e) so exp(x) == exp2(scaled score)
  bf16x8 qraw = __builtin_bit_cast(bf16x8,
      *reinterpret_cast<const uint4*>(xb + (size_t)(qw + ql) * FDIM + g * 8));
  bf16x8 qf;
#pragma unroll
  for (int e = 0; e < 8; ++e) qf[e] = (__bf16)((float)qraw[e] * LOG2E);

  f32x4 acc0 = {0.f, 0.f, 0.f, 0.f};  // O[row=4g+r][col=ql]
  f32x4 acc1 = {0.f, 0.f, 0.f, 0.f};  // O[row=4g+r][col=16+ql]
  float mrun = NEGBIG;
  float lrun = 0.f;

  const unsigned long long* brow = bits + (size_t)(qw + ql) * (SEQ / 64);
  const int bcol0 = jbase >> 6;

  // staging map: thread -> rows (2*pr, 2*pr+1), cols c4*4..c4*4+3
  const int pr = tid >> 3;  // 0..31
  const int c4 = tid & 7;   // 0..7
  const unsigned short* s0 = xb + (size_t)(jbase + 2 * pr) * FDIM + c4 * 4;
  const unsigned short* s1 = s0 + FDIM;

  uint2 r0 = *reinterpret_cast<const uint2*>(s0);
  uint2 r1 = *reinterpret_cast<const uint2*>(s1);
  unsigned long long wcur = brow[bcol0];

  for (int t = 0; t < NT; ++t) {
    __syncthreads();  // all waves done reading the tile
    // write staged tile: Kl rows 2pr,2pr+1 ; Vt packed u32 (j=2pr lo, 2pr+1 hi)
    *reinterpret_cast<uint2*>(&Kl[2 * pr][c4 * 4]) = r0;
    *reinterpret_cast<uint2*>(&Kl[2 * pr + 1][c4 * 4]) = r1;
    {
      unsigned q0 = r0.x, q1 = r0.y, q2 = r1.x, q3 = r1.y;
      unsigned* vb = reinterpret_cast<unsigned*>(&Vt[0][0]);
      vb[(c4 * 4 + 0) * 34 + pr] = (q0 & 0xffffu) | (q2 << 16);
      vb[(c4 * 4 + 1) * 34 + pr] = (q0 >> 16) | (q3 << 16);  // placeholder fixed below
      // NOTE: corrected packing:
      vb[(c4 * 4 + 1) * 34 + pr] = (q0 >> 16) | (q2 & 0xffff0000u);
      vb[(c4 * 4 + 2) * 34 + pr] = (q1 & 0xffffu) | (q3 << 16);
      vb[(c4 * 4 + 3) * 34 + pr] = (q1 >> 16) | (q3 & 0xffff0000u);
    }
    __syncthreads();  // tile visible

    // issue next tile's loads early (latency hides under compute below)
    if (t + 1 < NT) {
      s0 += 64 * FDIM;
      s1 += 64 * FDIM;
      r0 = *reinterpret_cast<const uint2*>(s0);
      r1 = *reinterpret_cast<const uint2*>(s1);
    }
    const unsigned long long w64 = wcur;
    if (t + 1 < NT) wcur = brow[bcol0 + t + 1];

    // swapped QK^T: lane (g,ql) holds S[q=ql][j = 16t4 + 4g + r] (log2 domain)
    f32x4 sc[4];
#pragma unroll
    for (int t4 = 0; t4 < 4; ++t4) {
      bf16x8 kf = __builtin_bit_cast(bf16x8,
          *reinterpret_cast<const uint4*>(&Kl[t4 * 16 + ql][g * 8]));
      f32x4 z = {0.f, 0.f, 0.f, 0.f};
      sc[t4] = __builtin_amdgcn_mfma_f32_16x16x32_bf16(kf, qf, z, 0, 0, 0);
    }

    // mask nibbles: bits {16*t4 + 4g + r}
    const unsigned long long wsh = w64 >> (4 * g);
    const unsigned mlo = (unsigned)wsh;
    const unsigned mhi = (unsigned)(wsh >> 32);
    const unsigned mt[4] = {mlo & 15u, (mlo >> 16) & 15u, mhi & 15u, (mhi >> 16) & 15u};

    float p[4][4];
    float xm[4];
#pragma unroll
    for (int t4 = 0; t4 < 4; ++t4) {
#pragma unroll
      for (int r = 0; r < 4; ++r) {
        float v = sc[t4][r];
        v = fmaxf(v, 0.2f * v);                       // leaky_relu (scale>0 commutes)
        v = (mt[t4] & (1u << r)) ? v : NEGBIG;        // adjacency mask
        p[t4][r] = v;
      }
      xm[t4] = fmaxf(fmaxf(p[t4][0], p[t4][1]), fmaxf(p[t4][2], p[t4][3]));
    }
    float tmax = fmaxf(fmaxf(xm[0], xm[1]), fmaxf(xm[2], xm[3]));
    tmax = fmaxf(tmax, __shfl_xor(tmax, 16));
    tmax = fmaxf(tmax, __shfl_xor(tmax, 32));

    // T13 defer-rescale: only rescale when max grew by > THR
    float mcur = mrun;
    if (!__all(tmax - mrun <= DEFER_THR)) {
      const float mnew = fmaxf(mrun, tmax);
      const float scale = __builtin_amdgcn_exp2f(mrun - mnew);
#pragma unroll
      for (int r = 0; r < 4; ++r) {
        const float s4 = __shfl(scale, g * 4 + r);
        acc0[r] *= s4;
        acc1[r] *= s4;
      }
      lrun *= scale;
      mrun = mnew;
      mcur = mnew;
    }

    float rsum = 0.f;
#pragma unroll
    for (int t4 = 0; t4 < 4; ++t4)
#pragma unroll
      for (int r = 0; r < 4; ++r) {
        const float e = __builtin_amdgcn_exp2f(p[t4][r] - mcur);
        p[t4][r] = e;
        rsum += e;
      }
    rsum += __shfl_xor(rsum, 16);
    rsum += __shfl_xor(rsum, 32);
    lrun += rsum;

    // PV: P(16x64) x V(64x32); A-frag slot (g, tp*4+r) <-> j = 32u + 16tp + 4g + r
#pragma unroll
    for (int u = 0; u < 2; ++u) {
      bf16x8 pa;
#pragma unroll
      for (int tp = 0; tp < 2; ++tp)
#pragma unroll
        for (int r = 0; r < 4; ++r)
          pa[tp * 4 + r] = (__bf16)p[2 * u + tp][r];
#pragma unroll
      for (int cc = 0; cc < 2; ++cc) {
        const unsigned short* vp = &Vt[cc * 16 + ql][u * 32 + g * 4];
        uint2 v0 = *reinterpret_cast<const uint2*>(vp);       // j = 32u + 4g + r
        uint2 v1 = *reinterpret_cast<const uint2*>(vp + 16);  // j = 32u + 16 + 4g + r
        uint4 vv = {v0.x, v0.y, v1.x, v1.y};
        bf16x8 vf = __builtin_bit_cast(bf16x8, vv);
        if (cc == 0)
          acc0 = __builtin_amdgcn_mfma_f32_16x16x32_bf16(pa, vf, acc0, 0, 0, 0);
        else
          acc1 = __builtin_amdgcn_mfma_f32_16x16x32_bf16(pa, vf, acc1, 0, 0, 0);
      }
    }
  }

  if (NSPLIT == 1) {
    // final: normalize and write out
#pragma unroll
    for (int r = 0; r < 4; ++r) {
      const float lr = __shfl(lrun, g * 4 + r);
      const float inv = 1.f / lr;
      const size_t o = ((size_t)b * SEQ + (size_t)(qw + g * 4 + r)) * FDIM + h * HD;
      dst[o + ql] = acc0[r] * inv;
      dst[o + 16 + ql] = acc1[r] * inv;
    }
  } else {
    float* Op = dst + (((size_t)blockIdx.z * (NB * NH) + bh) * SEQ) * HD;
#pragma unroll
    for (int r = 0; r < 4; ++r) {
      const int q = qw + 4 * g + r;
      Op[(size_t)q * HD + ql] = acc0[r];
      Op[(size_t)q * HD + 16 + ql] = acc1[r];
    }
    if (g == 0) {
      float2 v;
      v.x = mrun;
      v.y = lrun;
      *reinterpret_cast<float2*>(
          ml + ((size_t)blockIdx.z * NROWS + (size_t)bh * SEQ + qw + ql) * 2) = v;
    }
  }
}

// ---- combine partials (split path) ----
__global__ __launch_bounds__(256) void combine_kernel(
    const float* __restrict__ Op, const float* __restrict__ ml, float* __restrict__ out) {
  const int idx = blockIdx.x * 256 + threadIdx.x;  // unit: 4 floats
  const int row = idx >> 3;
  const int dc = (idx & 7) * 4;
  float2 ml0 = *reinterpret_cast<const float2*>(ml + (size_t)row * 2);
  float2 ml1 = *reinterpret_cast<const float2*>(ml + ((size_t)NROWS + row) * 2);
  const float m = fmaxf(ml0.x, ml1.x);
  float a0 = __builtin_amdgcn_exp2f(ml0.x - m);
  float a1 = __builtin_amdgcn_exp2f(ml1.x - m);
  const float l = ml0.y * a0 + ml1.y * a1;
  const float inv = 1.f / l;
  a0 *= inv;
  a1 *= inv;
  float4 o0 = *reinterpret_cast<const float4*>(Op + (size_t)row * HD + dc);
  float4 o1 = *reinterpret_cast<const float4*>(Op + (size_t)NROWS * HD + (size_t)row * HD + dc);
  float4 o;
  o.x = o0.x * a0 + o1.x * a1;
  o.y = o0.y * a0 + o1.y * a1;
  o.z = o0.z * a0 + o1.z * a1;
  o.w = o0.w * a0 + o1.w * a1;
  const int bh = row >> 12;
  const int q = row & (SEQ - 1);
  const int b = bh >> 2;
  const int h = bh & 3;
  *reinterpret_cast<float4*>(out + ((size_t)b * SEQ + q) * FDIM + h * HD + dc) = o;
}

extern "C" void kernel_launch(void* const* d_in, const int* in_sizes, int n_in,
                              void* d_out, int out_size, void* d_ws, size_t ws_size,
                              hipStream_t stream) {
  (void)in_sizes; (void)n_in; (void)out_size;
  const float* x = (const float*)d_in[0];
  const int* adj = (const int*)d_in[1];
  float* outp = (float*)d_out;

  unsigned short* xbf = (unsigned short*)d_ws;                                     // 2 MiB
  unsigned short* bits16 = (unsigned short*)((char*)d_ws + (2u << 20));            // 2 MiB
  float* Opart = (float*)((char*)d_ws + (4u << 20));                               // 8 MiB
  const size_t op_bytes = (size_t)2 * NROWS * HD * 4;
  float* mlbuf = (float*)((char*)d_ws + (4u << 20) + op_bytes);                    // 512 KiB
  const size_t need = (4u << 20) + op_bytes + (size_t)2 * NROWS * 2 * 4;
  const bool split = ws_size >= need;

  cvt_kernel<<<(NB * SEQ * FDIM) / (256 * 4), 256, 0, stream>>>(x, xbf);
  adjpack_kernel<<<(SEQ * SEQ) / (16 * 256), 256, 0, stream>>>(adj, bits16);

  const unsigned long long* bits = (const unsigned long long*)bits16;
  if (split) {
    dim3 grid(SEQ / 64, NB * NH, 2);
    gat_kernel<2><<<grid, 256, 0, stream>>>(xbf, bits, Opart, mlbuf);
    combine_kernel<<<(NROWS * 8) / 256, 256, 0, stream>>>(Opart, mlbuf, outp);
  } else {
    dim3 grid(SEQ / 64, NB * NH, 1);
    gat_kernel<1><<<grid, 256, 0, stream>>>(xbf, bits, outp, nullptr);
  }
}

// Round 3
// 75.137 us; speedup vs baseline: 1.6842x; 1.1041x over previous
//
#include <hip/hip_runtime.h>
#include <stdint.h>

#define SEQ 4096
#define FDIM 128
#define NH 4
#define HD 32
#define NB 2
#define NROWS (NB * NH * SEQ)  // 32768
#define LOG2E 1.4426950408889634f
#define NEGBIG (-1.0e30f)

typedef float f32x4 __attribute__((ext_vector_type(4)));
typedef __bf16 bf16x8 __attribute__((ext_vector_type(8)));

__device__ __forceinline__ unsigned short f2bf(float f) {
  unsigned int u = __builtin_bit_cast(unsigned int, f);
  return (unsigned short)((u + 0x7FFFu + ((u >> 16) & 1u)) >> 16);  // RTNE
}

// ---- pre-pass 1: fp32 -> bf16 ----
__global__ void cvt_kernel(const float* __restrict__ in, unsigned short* __restrict__ out) {
  int i = (blockIdx.x * 256 + threadIdx.x) * 4;
  float4 v = *reinterpret_cast<const float4*>(in + i);
  ushort4 o;
  o.x = f2bf(v.x); o.y = f2bf(v.y); o.z = f2bf(v.z); o.w = f2bf(v.w);
  *reinterpret_cast<ushort4*>(out + i) = o;
}

// ---- pre-pass 2: adjacency int32 -> bitmask; 16 ints/thread ----
__global__ void adjpack_kernel(const int* __restrict__ adj, unsigned short* __restrict__ bits16) {
  size_t t = (size_t)blockIdx.x * 256 + threadIdx.x;
  const uint4* p = reinterpret_cast<const uint4*>(adj) + t * 4;
  uint4 a = p[0], b = p[1], c = p[2], d = p[3];
  unsigned m = 0;
  m |= (a.x != 0) ? 1u : 0u;        m |= (a.y != 0) ? 2u : 0u;
  m |= (a.z != 0) ? 4u : 0u;        m |= (a.w != 0) ? 8u : 0u;
  m |= (b.x != 0) ? 16u : 0u;       m |= (b.y != 0) ? 32u : 0u;
  m |= (b.z != 0) ? 64u : 0u;       m |= (b.w != 0) ? 128u : 0u;
  m |= (c.x != 0) ? 256u : 0u;      m |= (c.y != 0) ? 512u : 0u;
  m |= (c.z != 0) ? 1024u : 0u;     m |= (c.w != 0) ? 2048u : 0u;
  m |= (d.x != 0) ? 4096u : 0u;     m |= (d.y != 0) ? 8192u : 0u;
  m |= (d.z != 0) ? 16384u : 0u;    m |= (d.w != 0) ? 32768u : 0u;
  bits16[t] = (unsigned short)m;
}

// ---- main fused attention kernel ----
// Grid: (SEQ/64, NB*NH, NSPLIT). 4 waves/block, each wave owns 16 q-rows.
// Static-max softmax: p = exp2(leaky(s)*log2e) unshifted; fp32 range suffices
// (max log2-score ~95 -> p<=4e28, sums <1e33 << 3.4e38).
template <int NSPLIT>
__global__ __launch_bounds__(256) void gat_kernel(
    const unsigned short* __restrict__ xbf,
    const unsigned long long* __restrict__ bits,
    float* __restrict__ dst,   // NSPLIT==1: final out ; else: Opart
    float* __restrict__ lbuf) {  // NSPLIT>1 only: [split][row] = l
  __shared__ __align__(16) unsigned short Kl[64][40];  // row-major K tile (80B rows)
  __shared__ __align__(16) unsigned Vt32[32 * 38];     // V^T: row c (stride 38 dw), u16 col j

  const int bh = blockIdx.y;
  const int b = bh >> 2;
  const int h = bh & 3;
  const int tid = threadIdx.x;
  const int wid = tid >> 6;
  const int lane = tid & 63;
  const int g = lane >> 4;
  const int ql = lane & 15;
  const int qw = blockIdx.x * 64 + wid * 16;
  const int jbase = blockIdx.z * (SEQ / NSPLIT);
  const int NT = (SEQ / NSPLIT) / 64;

  const unsigned short* xb = xbf + ((size_t)b * SEQ) * FDIM + h * HD;

  // Q fragment, pre-scaled by log2(e) so exp(x) == exp2(score)
  bf16x8 qraw = __builtin_bit_cast(bf16x8,
      *reinterpret_cast<const uint4*>(xb + (size_t)(qw + ql) * FDIM + g * 8));
  bf16x8 qf;
#pragma unroll
  for (int e = 0; e < 8; ++e) qf[e] = (__bf16)((float)qraw[e] * LOG2E);

  f32x4 acc0 = {0.f, 0.f, 0.f, 0.f};  // O[row=4g+r][col=ql]
  f32x4 acc1 = {0.f, 0.f, 0.f, 0.f};  // O[row=4g+r][col=16+ql]
  float lrun = 0.f;                   // per-lane partial sum (reduced at end)

  const unsigned long long* brow = bits + (size_t)(qw + ql) * (SEQ / 64);
  const int bcol0 = jbase >> 6;

  // staging map: thread -> rows (2*pr, 2*pr+1), cols c4*4..c4*4+3
  const int pr = tid >> 3;  // 0..31
  const int c4 = tid & 7;   // 0..7
  const unsigned short* s0 = xb + (size_t)(jbase + 2 * pr) * FDIM + c4 * 4;
  const unsigned short* s1 = s0 + FDIM;

  uint2 r0 = *reinterpret_cast<const uint2*>(s0);
  uint2 r1 = *reinterpret_cast<const uint2*>(s1);
  unsigned long long wcur = brow[bcol0];

  for (int t = 0; t < NT; ++t) {
    __syncthreads();  // all waves done reading previous tile
    *reinterpret_cast<uint2*>(&Kl[2 * pr][c4 * 4]) = r0;
    *reinterpret_cast<uint2*>(&Kl[2 * pr + 1][c4 * 4]) = r1;
    {
      unsigned q0 = r0.x, q1 = r0.y, q2 = r1.x, q3 = r1.y;
      Vt32[(c4 * 4 + 0) * 38 + pr] = (q0 & 0xffffu) | (q2 << 16);
      Vt32[(c4 * 4 + 1) * 38 + pr] = (q0 >> 16) | (q2 & 0xffff0000u);
      Vt32[(c4 * 4 + 2) * 38 + pr] = (q1 & 0xffffu) | (q3 << 16);
      Vt32[(c4 * 4 + 3) * 38 + pr] = (q1 >> 16) | (q3 & 0xffff0000u);
    }
    __syncthreads();  // tile visible

    // issue next tile's loads early (latency hides under compute below)
    if (t + 1 < NT) {
      s0 += 64 * FDIM;
      s1 += 64 * FDIM;
      r0 = *reinterpret_cast<const uint2*>(s0);
      r1 = *reinterpret_cast<const uint2*>(s1);
    }
    const unsigned long long w64 = wcur;
    if (t + 1 < NT) wcur = brow[bcol0 + t + 1];

    // swapped QK^T: lane (g,ql) holds S[q=ql][j = 16t4 + 4g + r] (log2 domain)
    f32x4 sc[4];
#pragma unroll
    for (int t4 = 0; t4 < 4; ++t4) {
      bf16x8 kf = __builtin_bit_cast(bf16x8,
          *reinterpret_cast<const uint4*>(&Kl[t4 * 16 + ql][g * 8]));
      f32x4 z = {0.f, 0.f, 0.f, 0.f};
      sc[t4] = __builtin_amdgcn_mfma_f32_16x16x32_bf16(kf, qf, z, 0, 0, 0);
    }

    // mask nibbles: bits {16*t4 + 4g + r}
    const unsigned long long wsh = w64 >> (4 * g);
    const unsigned mlo = (unsigned)wsh;
    const unsigned mhi = (unsigned)(wsh >> 32);
    const unsigned mt[4] = {mlo & 15u, (mlo >> 16) & 15u, mhi & 15u, (mhi >> 16) & 15u};

    float p[4][4];
    float rsum = 0.f;
#pragma unroll
    for (int t4 = 0; t4 < 4; ++t4) {
#pragma unroll
      for (int r = 0; r < 4; ++r) {
        float v = sc[t4][r];
        v = fmaxf(v, 0.2f * v);                         // leaky_relu
        const float e = __builtin_amdgcn_exp2f(v);      // unshifted exp2
        const float pe = (mt[t4] & (1u << r)) ? e : 0.f;  // adjacency mask
        p[t4][r] = pe;
        rsum += pe;
      }
    }
    lrun += rsum;

    // PV: P(16x64) x V(64x32); A-frag slot (g, tp*4+r) <-> j = 32u + 16tp + 4g + r
    const unsigned short* vbase = reinterpret_cast<const unsigned short*>(Vt32);
#pragma unroll
    for (int u = 0; u < 2; ++u) {
      bf16x8 pa;
#pragma unroll
      for (int tp = 0; tp < 2; ++tp)
#pragma unroll
        for (int r = 0; r < 4; ++r)
          pa[tp * 4 + r] = (__bf16)p[2 * u + tp][r];
#pragma unroll
      for (int cc = 0; cc < 2; ++cc) {
        const unsigned short* vp = vbase + (cc * 16 + ql) * 76 + u * 32 + g * 4;
        uint2 v0 = *reinterpret_cast<const uint2*>(vp);       // j = 32u + 4g + r
        uint2 v1 = *reinterpret_cast<const uint2*>(vp + 16);  // j = 32u + 16 + 4g + r
        uint4 vv = {v0.x, v0.y, v1.x, v1.y};
        bf16x8 vf = __builtin_bit_cast(bf16x8, vv);
        if (cc == 0)
          acc0 = __builtin_amdgcn_mfma_f32_16x16x32_bf16(pa, vf, acc0, 0, 0, 0);
        else
          acc1 = __builtin_amdgcn_mfma_f32_16x16x32_bf16(pa, vf, acc1, 0, 0, 0);
      }
    }
  }

  // reduce l across the 4 lane groups (each summed a disjoint j-partition)
  lrun += __shfl_xor(lrun, 16);
  lrun += __shfl_xor(lrun, 32);

  if (NSPLIT == 1) {
#pragma unroll
    for (int r = 0; r < 4; ++r) {
      const float lr = __shfl(lrun, g * 4 + r);
      const float inv = 1.f / lr;
      const size_t o = ((size_t)b * SEQ + (size_t)(qw + g * 4 + r)) * FDIM + h * HD;
      dst[o + ql] = acc0[r] * inv;
      dst[o + 16 + ql] = acc1[r] * inv;
    }
  } else {
    float* Op = dst + (((size_t)blockIdx.z * (NB * NH) + bh) * SEQ) * HD;
#pragma unroll
    for (int r = 0; r < 4; ++r) {
      const int q = qw + 4 * g + r;
      Op[(size_t)q * HD + ql] = acc0[r];
      Op[(size_t)q * HD + 16 + ql] = acc1[r];
    }
    if (g == 0)
      lbuf[(size_t)blockIdx.z * NROWS + (size_t)bh * SEQ + qw + ql] = lrun;
  }
}

// ---- combine partials (split path): out = sum(O_s) / sum(l_s) ----
template <int NSPLIT>
__global__ __launch_bounds__(256) void combine_kernel(
    const float* __restrict__ Op, const float* __restrict__ lbuf, float* __restrict__ out) {
  const int idx = blockIdx.x * 256 + threadIdx.x;  // unit: 4 floats
  const int row = idx >> 3;
  const int dc = (idx & 7) * 4;
  float lt = 0.f;
  float4 o = {0.f, 0.f, 0.f, 0.f};
#pragma unroll
  for (int s = 0; s < NSPLIT; ++s) {
    lt += lbuf[(size_t)s * NROWS + row];
    float4 v = *reinterpret_cast<const float4*>(
        Op + ((size_t)s * NROWS + row) * HD + dc);
    o.x += v.x; o.y += v.y; o.z += v.z; o.w += v.w;
  }
  const float inv = 1.f / lt;
  const int bh = row >> 12;
  const int q = row & (SEQ - 1);
  const int b = bh >> 2;
  const int h = bh & 3;
  float4 w;
  w.x = o.x * inv; w.y = o.y * inv; w.z = o.z * inv; w.w = o.w * inv;
  *reinterpret_cast<float4*>(out + ((size_t)b * SEQ + q) * FDIM + h * HD + dc) = w;
}

extern "C" void kernel_launch(void* const* d_in, const int* in_sizes, int n_in,
                              void* d_out, int out_size, void* d_ws, size_t ws_size,
                              hipStream_t stream) {
  (void)in_sizes; (void)n_in; (void)out_size;
  const float* x = (const float*)d_in[0];
  const int* adj = (const int*)d_in[1];
  float* outp = (float*)d_out;

  unsigned short* xbf = (unsigned short*)d_ws;                           // 2 MiB
  unsigned short* bits16 = (unsigned short*)((char*)d_ws + (2u << 20));  // 2 MiB
  float* Opart = (float*)((char*)d_ws + (4u << 20));
  auto need = [](int s) {
    return (size_t)(4u << 20) + (size_t)s * NROWS * HD * 4 + (size_t)s * NROWS * 4;
  };

  cvt_kernel<<<(NB * SEQ * FDIM) / (256 * 4), 256, 0, stream>>>(x, xbf);
  adjpack_kernel<<<(SEQ * SEQ) / (16 * 256), 256, 0, stream>>>(adj, bits16);

  const unsigned long long* bits = (const unsigned long long*)bits16;
  if (ws_size >= need(4)) {
    float* mlb = (float*)((char*)d_ws + (4u << 20) + (size_t)4 * NROWS * HD * 4);
    dim3 grid(SEQ / 64, NB * NH, 4);
    gat_kernel<4><<<grid, 256, 0, stream>>>(xbf, bits, Opart, mlb);
    combine_kernel<4><<<(NROWS * 8) / 256, 256, 0, stream>>>(Opart, mlb, outp);
  } else if (ws_size >= need(2)) {
    float* mlb = (float*)((char*)d_ws + (4u << 20) + (size_t)2 * NROWS * HD * 4);
    dim3 grid(SEQ / 64, NB * NH, 2);
    gat_kernel<2><<<grid, 256, 0, stream>>>(xbf, bits, Opart, mlb);
    combine_kernel<2><<<(NROWS * 8) / 256, 256, 0, stream>>>(Opart, mlb, outp);
  } else {
    dim3 grid(SEQ / 64, NB * NH, 1);
    gat_kernel<1><<<grid, 256, 0, stream>>>(xbf, bits, outp, nullptr);
  }
}

// Round 4
// 72.447 us; speedup vs baseline: 1.7467x; 1.0371x over previous
//
#include <hip/hip_runtime.h>
#include <stdint.h>

#define SEQ 4096
#define FDIM 128
#define NH 4
#define HD 32
#define NB 2
#define NROWS (NB * NH * SEQ)  // 32768
#define LOG2E 1.4426950408889634f

typedef float f32x4 __attribute__((ext_vector_type(4)));
typedef __bf16 bf16x8 __attribute__((ext_vector_type(8)));

__device__ __forceinline__ unsigned short f2bf(float f) {
  unsigned int u = __builtin_bit_cast(unsigned int, f);
  return (unsigned short)((u + 0x7FFFu + ((u >> 16) & 1u)) >> 16);  // RTNE
}

// ---- pre-pass 1: fp32 -> bf16 ----
__global__ void cvt_kernel(const float* __restrict__ in, unsigned short* __restrict__ out) {
  int i = (blockIdx.x * 256 + threadIdx.x) * 4;
  float4 v = *reinterpret_cast<const float4*>(in + i);
  ushort4 o;
  o.x = f2bf(v.x); o.y = f2bf(v.y); o.z = f2bf(v.z); o.w = f2bf(v.w);
  *reinterpret_cast<ushort4*>(out + i) = o;
}

// ---- pre-pass 2: adjacency int32 -> bitmask; 16 ints/thread ----
__global__ void adjpack_kernel(const int* __restrict__ adj, unsigned short* __restrict__ bits16) {
  size_t t = (size_t)blockIdx.x * 256 + threadIdx.x;
  const uint4* p = reinterpret_cast<const uint4*>(adj) + t * 4;
  uint4 a = p[0], b = p[1], c = p[2], d = p[3];
  unsigned m = 0;
  m |= (a.x != 0) ? 1u : 0u;        m |= (a.y != 0) ? 2u : 0u;
  m |= (a.z != 0) ? 4u : 0u;        m |= (a.w != 0) ? 8u : 0u;
  m |= (b.x != 0) ? 16u : 0u;       m |= (b.y != 0) ? 32u : 0u;
  m |= (b.z != 0) ? 64u : 0u;       m |= (b.w != 0) ? 128u : 0u;
  m |= (c.x != 0) ? 256u : 0u;      m |= (c.y != 0) ? 512u : 0u;
  m |= (c.z != 0) ? 1024u : 0u;     m |= (c.w != 0) ? 2048u : 0u;
  m |= (d.x != 0) ? 4096u : 0u;     m |= (d.y != 0) ? 8192u : 0u;
  m |= (d.z != 0) ? 16384u : 0u;    m |= (d.w != 0) ? 32768u : 0u;
  bits16[t] = (unsigned short)m;
}

// ---- main fused attention kernel ----
// Grid: (SEQ/64, NB*NH, NSPLIT). 4 waves/block, each wave owns 16 q-rows.
// Static-max softmax (fp32 range suffices); l via ones-MFMA (bf16-consistent
// with the PV numerator). V stored col-major with pi-permuted j so B-frags are
// single ds_read_b128 per (u,cc). Mask via sbfe-AND (2 ops/elem, no VCC).
template <int NSPLIT>
__global__ __launch_bounds__(256, 4) void gat_kernel(
    const unsigned short* __restrict__ xbf,
    const unsigned long long* __restrict__ bits,
    float* __restrict__ dst,     // NSPLIT==1: final out ; else: Opart
    float* __restrict__ lbuf) {  // NSPLIT>1 only: [split][row] = l
  __shared__ __align__(16) unsigned short Kl[64][40];   // K row-major, 80B rows (5120B)
  __shared__ __align__(16) unsigned short Vp[32 * 72];  // col-major, pi-permuted j (4608B)

  const int bh = blockIdx.y;
  const int b = bh >> 2;
  const int h = bh & 3;
  const int tid = threadIdx.x;
  const int wid = tid >> 6;
  const int lane = tid & 63;
  const int g = lane >> 4;
  const int ql = lane & 15;
  const int qw = blockIdx.x * 64 + wid * 16;
  const int jbase = blockIdx.z * (SEQ / NSPLIT);
  const int NT = (SEQ / NSPLIT) / 64;

  const unsigned short* xb = xbf + ((size_t)b * SEQ) * FDIM + h * HD;

  // Q fragment, pre-scaled by log2(e) so exp(x) == exp2(score)
  bf16x8 qraw = __builtin_bit_cast(bf16x8,
      *reinterpret_cast<const uint4*>(xb + (size_t)(qw + ql) * FDIM + g * 8));
  bf16x8 qf;
#pragma unroll
  for (int e = 0; e < 8; ++e) qf[e] = (__bf16)((float)qraw[e] * LOG2E);

  // ones B-fragment for the l row-sum MFMA
  bf16x8 ones;
#pragma unroll
  for (int e = 0; e < 8; ++e) ones[e] = (__bf16)1.0f;

  f32x4 acc0 = {0.f, 0.f, 0.f, 0.f};  // O[row=4g+r][col=ql]
  f32x4 acc1 = {0.f, 0.f, 0.f, 0.f};  // O[row=4g+r][col=16+ql]
  f32x4 accL = {0.f, 0.f, 0.f, 0.f};  // l[row=4g+r] (all cols identical)

  const unsigned long long* brow = bits + (size_t)(qw + ql) * (SEQ / 64);
  const int bcol0 = jbase >> 6;

  // staging map: thread -> rows (2*pr, 2*pr+1), cols 4*c4..4*c4+3
  const int pr = tid >> 3;  // 0..31
  const int c4 = tid & 7;   // 0..7
  const unsigned short* s0 = xb + (size_t)(jbase + 2 * pr) * FDIM + c4 * 4;

  // pi(j): j=[u|tp|g|r] (bits 5|4|3:2|1:0) -> [u|g|tp|r] (bits 5|4:3|2|1:0)
  // j0=2pr: u=pr>>4, tp=(pr>>3)&1, g2=(pr>>1)&3, r=2(pr&1); pi even, pi(j1)=pi+1
  const int pi0h = (32 * (pr >> 4) + 8 * ((pr >> 1) & 3) + 4 * ((pr >> 3) & 1) + 2 * (pr & 1)) >> 1;
  unsigned* vw = reinterpret_cast<unsigned*>(Vp) + pi0h;  // + col*36 per column

  uint2 r0 = *reinterpret_cast<const uint2*>(s0);
  uint2 r1 = *reinterpret_cast<const uint2*>(s0 + FDIM);
  unsigned long long wcur = brow[bcol0];

  const unsigned selA = 0x05040100u;  // [lo.b0, lo.b1, hi.b0, hi.b1]
  const unsigned selB = 0x07060302u;  // [lo.b2, lo.b3, hi.b2, hi.b3]

  for (int t = 0; t < NT; ++t) {
    __syncthreads();  // all waves done reading previous tile
    *reinterpret_cast<uint2*>(&Kl[2 * pr][c4 * 4]) = r0;
    *reinterpret_cast<uint2*>(&Kl[2 * pr + 1][c4 * 4]) = r1;
    vw[(4 * c4 + 0) * 36] = __builtin_amdgcn_perm(r1.x, r0.x, selA);
    vw[(4 * c4 + 1) * 36] = __builtin_amdgcn_perm(r1.x, r0.x, selB);
    vw[(4 * c4 + 2) * 36] = __builtin_amdgcn_perm(r1.y, r0.y, selA);
    vw[(4 * c4 + 3) * 36] = __builtin_amdgcn_perm(r1.y, r0.y, selB);
    __syncthreads();  // tile visible

    // issue next tile's loads early (latency hides under compute below)
    if (t + 1 < NT) {
      s0 += 64 * FDIM;
      r0 = *reinterpret_cast<const uint2*>(s0);
      r1 = *reinterpret_cast<const uint2*>(s0 + FDIM);
    }
    const unsigned long long w64 = wcur;
    if (t + 1 < NT) wcur = brow[bcol0 + t + 1];

    // swapped QK^T: lane (g,ql) holds S[q=ql][j = 16t4 + 4g + r] (log2 domain)
    f32x4 sc[4];
#pragma unroll
    for (int t4 = 0; t4 < 4; ++t4) {
      bf16x8 kf = __builtin_bit_cast(bf16x8,
          *reinterpret_cast<const uint4*>(&Kl[t4 * 16 + ql][g * 8]));
      f32x4 z = {0.f, 0.f, 0.f, 0.f};
      sc[t4] = __builtin_amdgcn_mfma_f32_16x16x32_bf16(kf, qf, z, 0, 0, 0);
    }

    // pre-shift mask word by 4g; then bit pos of (t4,r) = 16*(t4&1)+r (const)
    const unsigned long long wsh = w64 >> (4 * g);
    const unsigned mw[2] = {(unsigned)wsh, (unsigned)(wsh >> 32)};

    float pf[4][4];
#pragma unroll
    for (int t4 = 0; t4 < 4; ++t4) {
      const unsigned word = mw[t4 >> 1];
#pragma unroll
      for (int r = 0; r < 4; ++r) {
        float v = sc[t4][r];
        v = fmaxf(v, 0.2f * v);                      // leaky_relu
        float e = __builtin_amdgcn_exp2f(v);         // unshifted exp2
        const int pos = 16 * (t4 & 1) + r;
        const unsigned msk = (unsigned)((int)(word << (31 - pos)) >> 31);  // sbfe
        pf[t4][r] = __builtin_bit_cast(float, __builtin_bit_cast(unsigned, e) & msk);
      }
    }

    // PV: P(16x64) x V(64x32); A slot (g, tp*4+r) <-> j = 32u + 16tp + 4g + r.
    // Vp stores j at pi(j) so the B-frag is one b128 at [col*72 + u*32 + g*8].
#pragma unroll
    for (int u = 0; u < 2; ++u) {
      bf16x8 pa;
#pragma unroll
      for (int tp = 0; tp < 2; ++tp)
#pragma unroll
        for (int r = 0; r < 4; ++r)
          pa[tp * 4 + r] = (__bf16)pf[2 * u + tp][r];
      bf16x8 vf0 = __builtin_bit_cast(bf16x8,
          *reinterpret_cast<const uint4*>(&Vp[ql * 72 + u * 32 + g * 8]));
      bf16x8 vf1 = __builtin_bit_cast(bf16x8,
          *reinterpret_cast<const uint4*>(&Vp[(16 + ql) * 72 + u * 32 + g * 8]));
      acc0 = __builtin_amdgcn_mfma_f32_16x16x32_bf16(pa, vf0, acc0, 0, 0, 0);
      acc1 = __builtin_amdgcn_mfma_f32_16x16x32_bf16(pa, vf1, acc1, 0, 0, 0);
      accL = __builtin_amdgcn_mfma_f32_16x16x32_bf16(pa, ones, accL, 0, 0, 0);
    }
  }

  if (NSPLIT == 1) {
#pragma unroll
    for (int r = 0; r < 4; ++r) {
      const float inv = 1.f / accL[r];  // l for row 4g+r, already in place
      const size_t o = ((size_t)b * SEQ + (size_t)(qw + 4 * g + r)) * FDIM + h * HD;
      dst[o + ql] = acc0[r] * inv;
      dst[o + 16 + ql] = acc1[r] * inv;
    }
  } else {
    float* Op = dst + (((size_t)blockIdx.z * (NB * NH) + bh) * SEQ) * HD;
#pragma unroll
    for (int r = 0; r < 4; ++r) {
      const int q = qw + 4 * g + r;
      Op[(size_t)q * HD + ql] = acc0[r];
      Op[(size_t)q * HD + 16 + ql] = acc1[r];
    }
    if (ql == 0) {
#pragma unroll
      for (int r = 0; r < 4; ++r)
        lbuf[(size_t)blockIdx.z * NROWS + (size_t)bh * SEQ + qw + 4 * g + r] = accL[r];
    }
  }
}

// ---- combine partials (split path): out = sum(O_s) / sum(l_s) ----
template <int NSPLIT>
__global__ __launch_bounds__(256) void combine_kernel(
    const float* __restrict__ Op, const float* __restrict__ lbuf, float* __restrict__ out) {
  const int idx = blockIdx.x * 256 + threadIdx.x;  // unit: 4 floats
  const int row = idx >> 3;
  const int dc = (idx & 7) * 4;
  float lt = 0.f;
  float4 o = {0.f, 0.f, 0.f, 0.f};
#pragma unroll
  for (int s = 0; s < NSPLIT; ++s) {
    lt += lbuf[(size_t)s * NROWS + row];
    float4 v = *reinterpret_cast<const float4*>(
        Op + ((size_t)s * NROWS + row) * HD + dc);
    o.x += v.x; o.y += v.y; o.z += v.z; o.w += v.w;
  }
  const float inv = 1.f / lt;
  const int bh = row >> 12;
  const int q = row & (SEQ - 1);
  const int b = bh >> 2;
  const int h = bh & 3;
  float4 w;
  w.x = o.x * inv; w.y = o.y * inv; w.z = o.z * inv; w.w = o.w * inv;
  *reinterpret_cast<float4*>(out + ((size_t)b * SEQ + q) * FDIM + h * HD + dc) = w;
}

extern "C" void kernel_launch(void* const* d_in, const int* in_sizes, int n_in,
                              void* d_out, int out_size, void* d_ws, size_t ws_size,
                              hipStream_t stream) {
  (void)in_sizes; (void)n_in; (void)out_size;
  const float* x = (const float*)d_in[0];
  const int* adj = (const int*)d_in[1];
  float* outp = (float*)d_out;

  unsigned short* xbf = (unsigned short*)d_ws;                           // 2 MiB
  unsigned short* bits16 = (unsigned short*)((char*)d_ws + (2u << 20));  // 2 MiB
  float* Opart = (float*)((char*)d_ws + (4u << 20));
  auto need = [](int s) {
    return (size_t)(4u << 20) + (size_t)s * NROWS * HD * 4 + (size_t)s * NROWS * 4;
  };

  cvt_kernel<<<(NB * SEQ * FDIM) / (256 * 4), 256, 0, stream>>>(x, xbf);
  adjpack_kernel<<<(SEQ * SEQ) / (16 * 256), 256, 0, stream>>>(adj, bits16);

  const unsigned long long* bits = (const unsigned long long*)bits16;
  if (ws_size >= need(4)) {
    float* mlb = (float*)((char*)d_ws + (4u << 20) + (size_t)4 * NROWS * HD * 4);
    dim3 grid(SEQ / 64, NB * NH, 4);
    gat_kernel<4><<<grid, 256, 0, stream>>>(xbf, bits, Opart, mlb);
    combine_kernel<4><<<(NROWS * 8) / 256, 256, 0, stream>>>(Opart, mlb, outp);
  } else if (ws_size >= need(2)) {
    float* mlb = (float*)((char*)d_ws + (4u << 20) + (size_t)2 * NROWS * HD * 4);
    dim3 grid(SEQ / 64, NB * NH, 2);
    gat_kernel<2><<<grid, 256, 0, stream>>>(xbf, bits, Opart, mlb);
    combine_kernel<2><<<(NROWS * 8) / 256, 256, 0, stream>>>(Opart, mlb, outp);
  } else {
    dim3 grid(SEQ / 64, NB * NH, 1);
    gat_kernel<1><<<grid, 256, 0, stream>>>(xbf, bits, outp, nullptr);
  }
}